// Round 2
// baseline (1632.405 us; speedup 1.0000x reference)
//
#include <hip/hip_runtime.h>
#include <cstdint>

// ---------------- problem constants ----------------
// B=16, D_IN=1024, T=4096, CB_SIZE=8192, CB_DIM=256, SCALE=1024 (pool ratio 4)

#define BM 128
#define BN 128
#define BK 16
#define LDSP (BM + 4)

// d_out regions (f32 elements)
#define OUT_ZQ   0LL
#define OUT_LOSS 67108864LL   // commitment[16] then codebook[16]
#define OUT_IDX  67108896LL   // 16384 (written as float)
#define OUT_ZE   67125280LL   // 16*256*4096

// workspace layout (f32 elements)
#define W1_OFF   0LL          // 256*1024
#define W2_OFF   262144LL     // 1024*256
#define CN_OFF   524288LL     // 8192*256
#define C2_OFF   2621440LL    // 8192
#define E2_OFF   2629632LL    // 16384
#define LACC_OFF 2646016LL    // 16 (+pad)
#define IDX_OFF  2646080LL    // 16384 int32
#define IT_OFF   2695232LL    // 16384*256 (inter_z TRANSPOSED [n][d]; e_n in place)
#define BIG_OFF  6889536LL    // 16*1024*1024 (z_pooled, later table 8192*1024)
// overlays inside BIG (alive only after k_gemm_inter consumed z_pooled):
//   +8388608  : ushort[16384*256] bf16 queries  (2M f32 slots)
//   +10485760 : ushort[8192*256]  bf16 codebook (1M f32 slots)
//   +11534336 : float[256*16384]  subtile minima (4M f32 slots)
//   +15728640 : ushort[256*1024]  bf16 W1 (128K f32 slots)

typedef __attribute__((ext_vector_type(8))) short bf16x8;
typedef __attribute__((ext_vector_type(4))) float f32x4;

// ---------------- helpers ----------------
__device__ __forceinline__ float block_reduce_sum(float v, float* scratch) {
  __syncthreads();  // protect scratch reuse across calls
#pragma unroll
  for (int off = 32; off > 0; off >>= 1) v += __shfl_down(v, off, 64);
  int lane = threadIdx.x & 63, w = threadIdx.x >> 6;
  if (lane == 0) scratch[w] = v;
  __syncthreads();
  float r = 0.f;
  if (threadIdx.x == 0) {
    int nw = (blockDim.x + 63) >> 6;
    for (int i = 0; i < nw; i++) r += scratch[i];
  }
  return r;  // valid on thread 0
}

__device__ __forceinline__ unsigned long long shfl_xor_u64(unsigned long long v, int m) {
  unsigned lo = (unsigned)v, hi = (unsigned)(v >> 32);
  lo = __shfl_xor(lo, m, 64);
  hi = __shfl_xor(hi, m, 64);
  return ((unsigned long long)hi << 32) | lo;
}

__device__ __forceinline__ ushort f2bf(float f) {  // RNE float->bf16
  unsigned u = __float_as_uint(f);
  u += 0x7FFFu + ((u >> 16) & 1u);
  return (ushort)(u >> 16);
}

__device__ __forceinline__ unsigned f2s(float f) {  // order-preserving float->u32
  unsigned b = __float_as_uint(f);
  return b ^ (unsigned)(((int)b >> 31) | 0x80000000);
}

// ---------------- init ----------------
__global__ void k_init(float* __restrict__ lacc) {
  if (threadIdx.x < 16) lacc[threadIdx.x] = 0.f;
}

// ---------------- weight-norm prep: w = v * (g / ||v||_row) ----------------
__global__ void k_prep_w(const float* __restrict__ V, const float* __restrict__ G,
                         float* __restrict__ W, int RL) {
  int o = blockIdx.x, tid = threadIdx.x;
  float s = 0.f;
  for (int i = tid; i < RL; i += 256) { float v = V[(size_t)o * RL + i]; s = fmaf(v, v, s); }
  __shared__ float scratch[4];
  s = block_reduce_sum(s, scratch);
  __shared__ float sc;
  if (tid == 0) sc = G[o] / sqrtf(s);
  __syncthreads();
  float scale = sc;
  for (int i = tid; i < RL; i += 256) W[(size_t)o * RL + i] = V[(size_t)o * RL + i] * scale;
}

// ---------------- normalized codebook + row sq-norms ----------------
__global__ void k_prep_cn(const float* __restrict__ CB, float* __restrict__ Cn,
                          float* __restrict__ C2) {
  int k = blockIdx.x, tid = threadIdx.x;  // 256 threads = 256 dims
  float v = CB[(size_t)k * 256 + tid];
  __shared__ float scratch[4];
  float s = block_reduce_sum(v * v, scratch);
  __shared__ float sm;
  if (tid == 0) sm = fmaxf(sqrtf(s), 1e-12f);
  __syncthreads();
  float cn = v / sm;
  Cn[(size_t)k * 256 + tid] = cn;
  float s2 = block_reduce_sum(cn * cn, scratch);
  if (tid == 0) C2[k] = s2;
}

// ---------------- bf16 mirror of normalized codebook ----------------
__global__ void k_cvt_cn(const float* __restrict__ Cn, ushort* __restrict__ CB16) {
  int i = blockIdx.x * 256 + threadIdx.x;  // 524288 float4s
  float4 v = ((const float4*)Cn)[i];
  ushort4 o;
  o.x = f2bf(v.x); o.y = f2bf(v.y); o.z = f2bf(v.z); o.w = f2bf(v.w);
  ((ushort4*)CB16)[i] = o;
}

// ---------------- bf16 mirror of w1 (RNE), into dead z_pooled tail ----------------
__global__ void k_cvt_w1b(const float* __restrict__ W1, ushort* __restrict__ W1B) {
  int i = blockIdx.x * 256 + threadIdx.x;  // 65536 float4s
  float4 v = ((const float4*)W1)[i];
  ushort4 o;
  o.x = f2bf(v.x); o.y = f2bf(v.y); o.z = f2bf(v.z); o.w = f2bf(v.w);
  ((ushort4*)W1B)[i] = o;
}

// ---------------- pool z by 4 along t (commutes with 1x1 conv) ----------------
__global__ void k_pool(const float* __restrict__ Z, float* __restrict__ ZP) {
  int i = blockIdx.x * 256 + threadIdx.x;  // 16,777,216
  float4 v = ((const float4*)Z)[i];
  ZP[i] = (v.x + v.y + v.z + v.w) * 0.25f;
}

// ---------------- inter GEMM (Kahan), TRANSPOSED out: ITT[n][d] ----------------
#define IBM 64
#define IBN 64
__global__ __launch_bounds__(256) void k_gemm_inter(
    const float* __restrict__ W1, const float* __restrict__ ZP,
    const float* __restrict__ B1, float* __restrict__ ITT) {
  int tid = threadIdx.x;
  int n0g = blockIdx.x * IBN;  // 0..16383
  int m0 = blockIdx.y * IBM;   // 0..255
  int b = n0g >> 10, s0 = n0g & 1023;
  const float* Zb = ZP + ((size_t)b << 20);
  __shared__ float As[BK][IBM + 4];
  __shared__ float Bs[BK][IBN + 4];
  float acc[4][4], comp[4][4];
#pragma unroll
  for (int i = 0; i < 4; i++)
#pragma unroll
    for (int j = 0; j < 4; j++) { acc[i][j] = 0.f; comp[i][j] = 0.f; }
  int tx = tid & 15, ty = tid >> 4;
  int am = tid >> 2, ac4 = tid & 3;
  int bk = tid >> 4, bf4 = tid & 15;
  for (int k0 = 0; k0 < 1024; k0 += BK) {
    float4 a = *(const float4*)&W1[(size_t)(m0 + am) * 1024 + k0 + ac4 * 4];
    As[ac4 * 4 + 0][am] = a.x; As[ac4 * 4 + 1][am] = a.y;
    As[ac4 * 4 + 2][am] = a.z; As[ac4 * 4 + 3][am] = a.w;
    float4 v = *(const float4*)&Zb[(size_t)(k0 + bk) * 1024 + s0 + bf4 * 4];
    *(float4*)&Bs[bk][bf4 * 4] = v;
    __syncthreads();
    float ch[4][4];
#pragma unroll
    for (int i = 0; i < 4; i++)
#pragma unroll
      for (int j = 0; j < 4; j++) ch[i][j] = 0.f;
#pragma unroll
    for (int k = 0; k < BK; k++) {
      float4 a4 = *(const float4*)&As[k][ty * 4];
      float4 b4 = *(const float4*)&Bs[k][tx * 4];
      float av[4] = {a4.x, a4.y, a4.z, a4.w};
      float bv[4] = {b4.x, b4.y, b4.z, b4.w};
#pragma unroll
      for (int i = 0; i < 4; i++)
#pragma unroll
        for (int j = 0; j < 4; j++) ch[i][j] = fmaf(av[i], bv[j], ch[i][j]);
    }
    // Kahan-compensated fold of this K-chunk
#pragma unroll
    for (int i = 0; i < 4; i++)
#pragma unroll
      for (int j = 0; j < 4; j++) {
        float y = ch[i][j] - comp[i][j];
        float t = acc[i][j] + y;
        comp[i][j] = (t - acc[i][j]) - y;
        acc[i][j] = t;
      }
    __syncthreads();
  }
  float b0 = B1[m0 + ty * 4 + 0];
  float b1v = B1[m0 + ty * 4 + 1];
  float b2v = B1[m0 + ty * 4 + 2];
  float b3v = B1[m0 + ty * 4 + 3];
#pragma unroll
  for (int j = 0; j < 4; j++) {
    int n = n0g + tx * 4 + j;
    *(float4*)&ITT[(size_t)n * 256 + m0 + ty * 4] =
        make_float4(acc[0][j] + b0, acc[1][j] + b1v, acc[2][j] + b2v, acc[3][j] + b3v);
  }
}

// ---------------- normalize rows of ITT (queries), emit bf16 + e2 ----------------
__global__ void k_norm(float* __restrict__ ITT, ushort* __restrict__ QB,
                       float* __restrict__ E2) {
  int w = threadIdx.x >> 6, l = threadIdx.x & 63;
  int n = blockIdx.x * 4 + w;  // 4096 blocks
  float4 v = *(const float4*)&ITT[(size_t)n * 256 + l * 4];
  float s = fmaf(v.x, v.x, fmaf(v.y, v.y, fmaf(v.z, v.z, v.w * v.w)));
#pragma unroll
  for (int sh = 1; sh < 64; sh <<= 1) s += __shfl_xor(s, sh, 64);
  float m = fmaxf(sqrtf(s), 1e-12f);
  float4 o;
  o.x = v.x / m; o.y = v.y / m; o.z = v.z / m; o.w = v.w / m;
  *(float4*)&ITT[(size_t)n * 256 + l * 4] = o;
  ushort4 q;
  q.x = f2bf(o.x); q.y = f2bf(o.y); q.z = f2bf(o.z); q.w = f2bf(o.w);
  *(ushort4*)&QB[(size_t)n * 256 + l * 4] = q;
  float s2 = fmaf(o.x, o.x, fmaf(o.y, o.y, fmaf(o.z, o.z, o.w * o.w)));
#pragma unroll
  for (int sh = 1; sh < 64; sh <<= 1) s2 += __shfl_xor(s2, sh, 64);
  if (l == 0) E2[n] = s2;
}

// ---------------- GEMM1 via MFMA: z_e = W1 @ z + b1 (bf16 inputs, f32 acc) ----------------
// Block: 256m x 128n, K=1024. 4 waves, each 128m x 64n (8x4 of 16x16x32 bf16).
// A (W1 bf16) direct global->reg (L2-resident). B (z f32 [k][t]) staged in LDS,
// fragments assembled via scalar reads + truncate-pack. Epilogue transposed via LDS.
#define G1_BN 128
__global__ __launch_bounds__(256) void k_gemm1m(
    const ushort* __restrict__ W1B, const float* __restrict__ Z,
    const float* __restrict__ B1, float* __restrict__ ZE) {
  int tid = threadIdx.x;
  int n0g = blockIdx.x * G1_BN;  // global t across batches
  int b = n0g >> 12, t0 = n0g & 4095;
  const float* Zb = Z + ((size_t)b << 22);  // b*1024*4096
  __shared__ float Bs[32][129];
  __shared__ float LT[4][16][65];
  int lane = tid & 63, wid = tid >> 6;
  int wm = wid >> 1, wn = wid & 1;  // wave: m-half (128 rows), n-half (64 cols)
  int lc = lane & 15, lh = lane >> 4;
  f32x4 acc[8][4];
#pragma unroll
  for (int i = 0; i < 8; i++)
#pragma unroll
    for (int j = 0; j < 4; j++) acc[i][j] = (f32x4){0.f, 0.f, 0.f, 0.f};
  // A fragment base: row m = wm*128 + i*16 + lc, k-offset lh*8
  const ushort* Abase = W1B + (size_t)(wm * 128 + lc) * 1024 + lh * 8;
  for (int k0 = 0; k0 < 1024; k0 += 32) {
    // issue global loads first (B staging data + A fragments)
    float4 zv[4];
#pragma unroll
    for (int it = 0; it < 4; it++) {
      int q = it * 256 + tid;
      int k = q >> 5, tf4 = q & 31;
      zv[it] = *(const float4*)&Zb[(size_t)(k0 + k) * 4096 + t0 + tf4 * 4];
    }
    bf16x8 af[8];
#pragma unroll
    for (int i = 0; i < 8; i++)
      af[i] = *(const bf16x8*)(Abase + (size_t)i * 16384 + k0);
    __syncthreads();  // prior iteration's Bs reads done
#pragma unroll
    for (int it = 0; it < 4; it++) {
      int q = it * 256 + tid;
      int k = q >> 5, tf4 = q & 31;
      *(float4*)&Bs[k][tf4 * 4] = zv[it];
    }
    __syncthreads();
    // build B fragments: lane lc -> col, lh -> k-octet; truncate f32->bf16
    bf16x8 bq[4];
#pragma unroll
    for (int j = 0; j < 4; j++) {
      int col = wn * 64 + j * 16 + lc;
      unsigned bw[4];
#pragma unroll
      for (int p = 0; p < 4; p++) {
        unsigned u0 = __float_as_uint(Bs[lh * 8 + 2 * p + 0][col]);
        unsigned u1 = __float_as_uint(Bs[lh * 8 + 2 * p + 1][col]);
        bw[p] = (u1 & 0xFFFF0000u) | (u0 >> 16);
      }
      bq[j] = *reinterpret_cast<bf16x8*>(bw);
    }
#pragma unroll
    for (int i = 0; i < 8; i++)
#pragma unroll
      for (int j = 0; j < 4; j++)
        acc[i][j] = __builtin_amdgcn_mfma_f32_16x16x32_bf16(af[i], bq[j], acc[i][j], 0, 0, 0);
  }
  // epilogue: per-wave LDS transpose so global stores are 64-lane contiguous
  float* C = ZE + ((size_t)b << 20) * 1;  // b*256*4096 handled below
  C = ZE + (size_t)b * 256 * 4096;
#pragma unroll 1
  for (int i = 0; i < 8; i++) {
    __syncthreads();
#pragma unroll
    for (int j = 0; j < 4; j++)
#pragma unroll
      for (int r = 0; r < 4; r++)
        LT[wid][lh * 4 + r][j * 16 + lc] = acc[i][j][r];
    __syncthreads();
#pragma unroll 1
    for (int mr = 0; mr < 16; mr++) {
      int m = wm * 128 + i * 16 + mr;
      float bias = B1[m];
      C[(size_t)m * 4096 + t0 + wn * 64 + lane] = LT[wid][mr][lane] + bias;
    }
  }
}

// ---------------- dist approx: bf16 MFMA, per-32-candidate-subtile minima ----------------
// A = CnBf [8192][256] (M=candidates), B = QBf [16384][256] (N=queries)
// score = c2[m] - 2*dot_bf16;  TMIN[sub 256][n 16384] = min over subtile
#define DBKP 72  // 64 + 8 bf16 pad (16B) -> row stride 144B
__global__ __launch_bounds__(256) void k_dist_approx(
    const ushort* __restrict__ CnB, const ushort* __restrict__ QB,
    const float* __restrict__ C2, float* __restrict__ TMIN) {
  int tid = threadIdx.x;
  int n0 = blockIdx.x * 128;  // queries
  int m0 = blockIdx.y * 128;  // candidates
  __shared__ __align__(16) ushort As[128][DBKP];  // candidates
  __shared__ __align__(16) ushort Bs[128][DBKP];  // queries
  __shared__ float c2s[128];
  __shared__ float smin[4][128];
  int lane = tid & 63, wid = tid >> 6;
  int wm = wid >> 1, wn = wid & 1;
  int lc = lane & 15, lh = lane >> 4;
  f32x4 acc[4][4];
#pragma unroll
  for (int i = 0; i < 4; i++)
#pragma unroll
    for (int j = 0; j < 4; j++) acc[i][j] = (f32x4){0.f, 0.f, 0.f, 0.f};
  if (tid < 128) c2s[tid] = C2[m0 + tid];
  int row = tid >> 1, chunk = tid & 1;
  const ushort* gA = CnB + (size_t)(m0 + row) * 256 + chunk * 32;
  const ushort* gB = QB + (size_t)(n0 + row) * 256 + chunk * 32;
  for (int k0 = 0; k0 < 256; k0 += 64) {
    float4 a0 = *(const float4*)(gA + k0);
    float4 a1 = *(const float4*)(gA + k0 + 8);
    float4 a2 = *(const float4*)(gA + k0 + 16);
    float4 a3 = *(const float4*)(gA + k0 + 24);
    float4 b0 = *(const float4*)(gB + k0);
    float4 b1 = *(const float4*)(gB + k0 + 8);
    float4 b2 = *(const float4*)(gB + k0 + 16);
    float4 b3 = *(const float4*)(gB + k0 + 24);
    __syncthreads();  // prior iteration's frag reads done
    *(float4*)&As[row][chunk * 32 + 0] = a0;
    *(float4*)&As[row][chunk * 32 + 8] = a1;
    *(float4*)&As[row][chunk * 32 + 16] = a2;
    *(float4*)&As[row][chunk * 32 + 24] = a3;
    *(float4*)&Bs[row][chunk * 32 + 0] = b0;
    *(float4*)&Bs[row][chunk * 32 + 8] = b1;
    *(float4*)&Bs[row][chunk * 32 + 16] = b2;
    *(float4*)&Bs[row][chunk * 32 + 24] = b3;
    __syncthreads();
#pragma unroll
    for (int kk = 0; kk < 64; kk += 32) {
      bf16x8 af[4], bfr[4];
#pragma unroll
      for (int i = 0; i < 4; i++) {
        af[i] = *(const bf16x8*)&As[wm * 64 + i * 16 + lc][kk + lh * 8];
        bfr[i] = *(const bf16x8*)&Bs[wn * 64 + i * 16 + lc][kk + lh * 8];
      }
#pragma unroll
      for (int i = 0; i < 4; i++)
#pragma unroll
        for (int j = 0; j < 4; j++)
          acc[i][j] = __builtin_amdgcn_mfma_f32_16x16x32_bf16(af[i], bfr[j], acc[i][j], 0, 0, 0);
    }
  }
  // per-lane min over (i, r) split into 32-row halves; D: row=(lh*4+r), col=lc
  float vmin0[4], vmin1[4];
#pragma unroll
  for (int j = 0; j < 4; j++) {
    float mA = 3.4e38f, mB = 3.4e38f;
#pragma unroll
    for (int i = 0; i < 4; i++) {
#pragma unroll
      for (int r = 0; r < 4; r++) {
        float s = c2s[wm * 64 + i * 16 + lh * 4 + r] - 2.f * acc[i][j][r];
        if (i < 2) mA = fminf(mA, s); else mB = fminf(mB, s);
      }
    }
    vmin0[j] = mA; vmin1[j] = mB;
  }
#pragma unroll
  for (int j = 0; j < 4; j++) {
    vmin0[j] = fminf(vmin0[j], __shfl_xor(vmin0[j], 16, 64));
    vmin0[j] = fminf(vmin0[j], __shfl_xor(vmin0[j], 32, 64));
    vmin1[j] = fminf(vmin1[j], __shfl_xor(vmin1[j], 16, 64));
    vmin1[j] = fminf(vmin1[j], __shfl_xor(vmin1[j], 32, 64));
  }
  // writer: lane handles j == lh for its column lc
  float w0 = (lh == 0) ? vmin0[0] : (lh == 1) ? vmin0[1] : (lh == 2) ? vmin0[2] : vmin0[3];
  float w1 = (lh == 0) ? vmin1[0] : (lh == 1) ? vmin1[1] : (lh == 2) ? vmin1[2] : vmin1[3];
  smin[wm * 2 + 0][wn * 64 + lh * 16 + lc] = w0;
  smin[wm * 2 + 1][wn * 64 + lh * 16 + lc] = w1;
  __syncthreads();
  if (tid < 128) {
#pragma unroll
    for (int sub = 0; sub < 4; sub++)
      TMIN[(size_t)(blockIdx.y * 4 + sub) * 16384 + n0 + tid] = smin[sub][tid];
  }
}

// ---------------- exact refine: fp64 dots on qualifying subtiles ----------------
#define RMARGIN 0.035f  // > 2*eps, eps <= 2^-6 (worst-case bf16 rounding, |q|=|c|=1)
__global__ __launch_bounds__(128) void k_refine(
    const float* __restrict__ TMIN, const float* __restrict__ ITT,
    const float* __restrict__ Cn, const float* __restrict__ C2,
    const float* __restrict__ E2, int* __restrict__ IDX, float* __restrict__ OUTI) {
  int n = blockIdx.x, t = threadIdx.x;
  __shared__ __align__(16) float qs[256];
  __shared__ float tm[256];
  __shared__ int qlist[256];
  __shared__ int qcount;
  __shared__ float mus[2];
  __shared__ double parts[4][32];
  qs[t] = ITT[(size_t)n * 256 + t];
  qs[t + 128] = ITT[(size_t)n * 256 + 128 + t];
  tm[t] = TMIN[(size_t)t * 16384 + n];
  tm[t + 128] = TMIN[(size_t)(t + 128) * 16384 + n];
  if (t == 0) qcount = 0;
  __syncthreads();
  float mu = fminf(tm[t], tm[t + 128]);
#pragma unroll
  for (int s = 1; s < 64; s <<= 1) mu = fminf(mu, __shfl_xor(mu, s, 64));
  if ((t & 63) == 0) mus[t >> 6] = mu;
  __syncthreads();
  float thr = fminf(mus[0], mus[1]) + RMARGIN;
  for (int s = t; s < 256; s += 128)
    if (tm[s] <= thr) { int p = atomicAdd(&qcount, 1); qlist[p] = s; }
  __syncthreads();
  int Q = qcount;
  unsigned long long best = ~0ull;
  float e2n = E2[n];
  int c = t & 31, kc = t >> 5;
  for (int qi = 0; qi < Q; qi++) {
    int sub = qlist[qi];
    int m = sub * 32 + c;
    const float* cr = Cn + (size_t)m * 256 + kc * 64;
    const float* qq = qs + kc * 64;
    double p = 0.0;
#pragma unroll 4
    for (int k = 0; k < 64; k += 4) {
      float4 c4 = *(const float4*)&cr[k];
      float4 q4 = *(const float4*)&qq[k];
      p += (double)c4.x * (double)q4.x + (double)c4.y * (double)q4.y +
           (double)c4.z * (double)q4.z + (double)c4.w * (double)q4.w;
    }
    parts[kc][c] = p;
    __syncthreads();
    if (t < 32) {
      double dot = (parts[0][t] + parts[1][t]) + (parts[2][t] + parts[3][t]);
      float dist = (float)((double)e2n - 2.0 * dot + (double)C2[sub * 32 + t]);
      unsigned long long pk =
          ((unsigned long long)f2s(dist) << 32) | (unsigned)(sub * 32 + t);
      best = (pk < best) ? pk : best;
    }
    __syncthreads();
  }
  if (t < 32) {
#pragma unroll
    for (int s = 1; s <= 16; s <<= 1) {
      unsigned long long o = shfl_xor_u64(best, s);
      best = (o < best) ? o : best;
    }
    if (t == 0) {
      int idx = (int)(best & 0xFFFFFFFFull);
      IDX[n] = idx;
      OUTI[n] = (float)idx;
    }
  }
}

// ---------------- table GEMM: TT[k][o] = sum_d CB[k][d] * W2[o][d] ----------------
__global__ __launch_bounds__(256) void k_table(
    const float* __restrict__ CB, const float* __restrict__ W2,
    float* __restrict__ TT) {
  int tid = threadIdx.x;
  int n0 = blockIdx.x * BN;  // o tile (1024 -> 8)
  int m0 = blockIdx.y * BM;  // codebook tile (8192 -> 64)
  __shared__ float As[BK][LDSP];
  __shared__ float Bs[BK][LDSP];
  float acc[8][8];
#pragma unroll
  for (int i = 0; i < 8; i++)
#pragma unroll
    for (int j = 0; j < 8; j++) acc[i][j] = 0.f;
  int tx = tid & 15, ty = tid >> 4;
  int am = tid >> 1, ac4 = tid & 1;
  for (int k0 = 0; k0 < 256; k0 += BK) {
#pragma unroll
    for (int h = 0; h < 2; h++) {
      int c4 = ac4 + h * 2;
      float4 a = *(const float4*)&CB[(size_t)(m0 + am) * 256 + k0 + c4 * 4];
      As[c4 * 4 + 0][am] = a.x; As[c4 * 4 + 1][am] = a.y;
      As[c4 * 4 + 2][am] = a.z; As[c4 * 4 + 3][am] = a.w;
      float4 b = *(const float4*)&W2[(size_t)(n0 + am) * 256 + k0 + c4 * 4];
      Bs[c4 * 4 + 0][am] = b.x; Bs[c4 * 4 + 1][am] = b.y;
      Bs[c4 * 4 + 2][am] = b.z; Bs[c4 * 4 + 3][am] = b.w;
    }
    __syncthreads();
#pragma unroll
    for (int k = 0; k < BK; k++) {
      float4 a0 = *(const float4*)&As[k][ty * 4];
      float4 a1 = *(const float4*)&As[k][ty * 4 + 64];
      float4 b0 = *(const float4*)&Bs[k][tx * 4];
      float4 b1 = *(const float4*)&Bs[k][tx * 4 + 64];
      float av[8] = {a0.x, a0.y, a0.z, a0.w, a1.x, a1.y, a1.z, a1.w};
      float bv[8] = {b0.x, b0.y, b0.z, b0.w, b1.x, b1.y, b1.z, b1.w};
#pragma unroll
      for (int i = 0; i < 8; i++)
#pragma unroll
        for (int j = 0; j < 8; j++) acc[i][j] = fmaf(av[i], bv[j], acc[i][j]);
    }
    __syncthreads();
  }
#pragma unroll
  for (int i = 0; i < 8; i++) {
    int m = m0 + ((i < 4) ? (ty * 4 + i) : (64 + ty * 4 + (i - 4)));
    *(float4*)&TT[(size_t)m * 1024 + n0 + tx * 4] =
        make_float4(acc[i][0], acc[i][1], acc[i][2], acc[i][3]);
    *(float4*)&TT[(size_t)m * 1024 + n0 + 64 + tx * 4] =
        make_float4(acc[i][4], acc[i][5], acc[i][6], acc[i][7]);
  }
}

// ---------------- gather table rows + linear upsample + bias ----------------
__global__ __launch_bounds__(256) void k_upsample(
    const float* __restrict__ TT, const int* __restrict__ IDX,
    const float* __restrict__ B2, float* __restrict__ OUT) {
  int tid = threadIdx.x;
  int t0 = blockIdx.x * 64;
  int o0 = blockIdx.y * 64;
  int b = blockIdx.z;
  int s_lo = (t0 == 0) ? 0 : (t0 / 4 - 1);
  int s_hi = min(t0 / 4 + 16, 1023);
  int cnt = s_hi - s_lo + 1;  // <= 18
  __shared__ float rows[18 * 65];
  for (int q = tid; q < cnt * 64; q += 256) {
    int r = q >> 6, oc = q & 63;
    int ti = IDX[b * 1024 + s_lo + r];
    rows[r * 65 + oc] = TT[(size_t)ti * 1024 + o0 + oc];
  }
  __syncthreads();
  int tl = tid & 63, og = tid >> 6;
  int t = t0 + tl;
  float src = fmaxf((t + 0.5f) * 0.25f - 0.5f, 0.f);
  int i0 = (int)src;
  float fr = src - (float)i0;
  int i1 = min(i0 + 1, 1023);
  int r0 = i0 - s_lo, r1 = i1 - s_lo;
  float* outb = OUT + (size_t)b * 1024 * 4096;
#pragma unroll
  for (int j = 0; j < 16; j++) {
    int o = o0 + og * 16 + j;
    float v = rows[r0 * 65 + og * 16 + j] * (1.f - fr) +
              rows[r1 * 65 + og * 16 + j] * fr + B2[o];
    outb[(size_t)o * 4096 + t] = v;
  }
}

// ---------------- loss: mean((z_e - upsample(cb[idx]))^2) per batch ----------------
__global__ __launch_bounds__(256) void k_loss(
    const float* __restrict__ ZE, const float* __restrict__ CB,
    const int* __restrict__ IDX, float* __restrict__ LACC) {
  int tid = threadIdx.x;
  int t0 = blockIdx.x * 64;
  int b = blockIdx.y;
  int s_lo = (t0 == 0) ? 0 : (t0 / 4 - 1);
  int s_hi = min(t0 / 4 + 16, 1023);
  int cnt = s_hi - s_lo + 1;
  __shared__ float crow[18 * 257];
  for (int q = tid; q < cnt * 256; q += 256) {
    int r = q >> 8, d = q & 255;
    int ti = IDX[b * 1024 + s_lo + r];
    crow[r * 257 + d] = CB[(size_t)ti * 256 + d];
  }
  __syncthreads();
  int tl = tid & 63, dg = tid >> 6;
  int t = t0 + tl;
  float src = fmaxf((t + 0.5f) * 0.25f - 0.5f, 0.f);
  int i0 = (int)src;
  float fr = src - (float)i0;
  int i1 = min(i0 + 1, 1023);
  int r0 = i0 - s_lo, r1 = i1 - s_lo;
  const float* zeb = ZE + (size_t)b * 256 * 4096;
  float acc = 0.f;
  for (int j = 0; j < 64; j++) {
    int d = dg * 64 + j;
    float zq = crow[r0 * 257 + d] * (1.f - fr) + crow[r1 * 257 + d] * fr;
    float diff = zeb[(size_t)d * 4096 + t] - zq;
    acc = fmaf(diff, diff, acc);
  }
  __shared__ float scratch[4];
  acc = block_reduce_sum(acc, scratch);
  if (tid == 0) atomicAdd(&LACC[b], acc);
}

__global__ void k_loss_final(const float* __restrict__ LACC, float* __restrict__ OUTL) {
  int t = threadIdx.x;  // 32
  OUTL[t] = LACC[t & 15] * (1.f / 1048576.f);
}

// ---------------- launch ----------------
extern "C" void kernel_launch(void* const* d_in, const int* in_sizes, int n_in,
                              void* d_out, int out_size, void* d_ws, size_t ws_size,
                              hipStream_t stream) {
  (void)in_sizes; (void)n_in; (void)out_size; (void)ws_size;
  const float* z   = (const float*)d_in[0];
  const float* ipv = (const float*)d_in[1];
  const float* ipg = (const float*)d_in[2];
  const float* ipb = (const float*)d_in[3];
  const float* opv = (const float*)d_in[4];
  const float* opg = (const float*)d_in[5];
  const float* opb = (const float*)d_in[6];
  const float* cb  = (const float*)d_in[7];

  float* out = (float*)d_out;
  float* ws  = (float*)d_ws;

  float* w1 = ws + W1_OFF;
  float* w2 = ws + W2_OFF;
  float* cn = ws + CN_OFF;
  float* c2 = ws + C2_OFF;
  float* e2 = ws + E2_OFF;
  float* lacc = ws + LACC_OFF;
  int*   idx = (int*)(ws + IDX_OFF);
  float* itt = ws + IT_OFF;
  float* big = ws + BIG_OFF;  // z_pooled, then table
  ushort* qbf  = (ushort*)(ws + BIG_OFF + 8388608LL);
  ushort* cbf  = (ushort*)(ws + BIG_OFF + 10485760LL);
  float*  tmin = ws + BIG_OFF + 11534336LL;
  ushort* w1b  = (ushort*)(ws + BIG_OFF + 15728640LL);

  float* out_zq = out + OUT_ZQ;
  float* out_loss = out + OUT_LOSS;
  float* out_idx = out + OUT_IDX;
  float* out_ze = out + OUT_ZE;

  hipLaunchKernelGGL(k_init, dim3(1), dim3(64), 0, stream, lacc);
  hipLaunchKernelGGL(k_prep_w, dim3(256), dim3(256), 0, stream, ipv, ipg, w1, 1024);
  hipLaunchKernelGGL(k_prep_w, dim3(1024), dim3(256), 0, stream, opv, opg, w2, 256);
  hipLaunchKernelGGL(k_prep_cn, dim3(8192), dim3(256), 0, stream, cb, cn, c2);
  hipLaunchKernelGGL(k_pool, dim3(65536), dim3(256), 0, stream, z, big);
  hipLaunchKernelGGL(k_gemm_inter, dim3(256, 4), dim3(256), 0, stream, w1, big, ipb, itt);
  hipLaunchKernelGGL(k_norm, dim3(4096), dim3(256), 0, stream, itt, qbf, e2);
  hipLaunchKernelGGL(k_cvt_cn, dim3(2048), dim3(256), 0, stream, cn, cbf);
  hipLaunchKernelGGL(k_cvt_w1b, dim3(256), dim3(256), 0, stream, w1, w1b);
  hipLaunchKernelGGL(k_gemm1m, dim3(512), dim3(256), 0, stream, w1b, z, ipb, out_ze);
  hipLaunchKernelGGL(k_dist_approx, dim3(128, 64), dim3(256), 0, stream, cbf, qbf, c2, tmin);
  hipLaunchKernelGGL(k_refine, dim3(16384), dim3(128), 0, stream, tmin, itt, cn, c2, e2,
                     idx, out_idx);
  hipLaunchKernelGGL(k_table, dim3(8, 64), dim3(256), 0, stream, cb, w2, big);
  hipLaunchKernelGGL(k_upsample, dim3(64, 16, 16), dim3(256), 0, stream, big, idx, opb, out_zq);
  hipLaunchKernelGGL(k_loss, dim3(64, 16), dim3(256), 0, stream, out_ze, cb, idx, lacc);
  hipLaunchKernelGGL(k_loss_final, dim3(1), dim3(32), 0, stream, lacc, out_loss);
}

// Round 3
// 1292.220 us; speedup vs baseline: 1.2633x; 1.2633x over previous
//
#include <hip/hip_runtime.h>
#include <cstdint>

// ---------------- problem constants ----------------
// B=16, D_IN=1024, T=4096, CB_SIZE=8192, CB_DIM=256, SCALE=1024 (pool ratio 4)

#define BM 128
#define BN 128
#define BK 16
#define LDSP (BM + 4)

// d_out regions (f32 elements)
#define OUT_ZQ   0LL
#define OUT_LOSS 67108864LL   // commitment[16] then codebook[16]
#define OUT_IDX  67108896LL   // 16384 (written as float)
#define OUT_ZE   67125280LL   // 16*256*4096

// workspace layout (f32 elements)
#define W1_OFF   0LL          // 256*1024
#define W2_OFF   262144LL     // 1024*256
#define CN_OFF   524288LL     // 8192*256
#define C2_OFF   2621440LL    // 8192
#define E2_OFF   2629632LL    // 16384
#define LACC_OFF 2646016LL    // 16 (+pad)
#define IDX_OFF  2646080LL    // 16384 int32
#define IT_OFF   2695232LL    // 16384*256 (inter_z TRANSPOSED [n][d]; e_n in place)
#define BIG_OFF  6889536LL    // 16*1024*1024 (z_pooled, later table 8192*1024)
// overlays inside BIG (alive only after k_gemm_inter consumed z_pooled):
//   +8388608  : ushort[16384*256] bf16 queries  (2M f32 slots)
//   +10485760 : ushort[8192*256]  bf16 codebook (1M f32 slots)
//   +11534336 : float[256*16384]  subtile minima (4M f32 slots)
//   +15728640 : ushort[256*1024]  bf16 W1 (128K f32 slots)

typedef __attribute__((ext_vector_type(8))) short bf16x8;
typedef __attribute__((ext_vector_type(4))) float f32x4;

// ---------------- helpers ----------------
__device__ __forceinline__ float block_reduce_sum(float v, float* scratch) {
  __syncthreads();  // protect scratch reuse across calls
#pragma unroll
  for (int off = 32; off > 0; off >>= 1) v += __shfl_down(v, off, 64);
  int lane = threadIdx.x & 63, w = threadIdx.x >> 6;
  if (lane == 0) scratch[w] = v;
  __syncthreads();
  float r = 0.f;
  if (threadIdx.x == 0) {
    int nw = (blockDim.x + 63) >> 6;
    for (int i = 0; i < nw; i++) r += scratch[i];
  }
  return r;  // valid on thread 0
}

__device__ __forceinline__ unsigned long long shfl_xor_u64(unsigned long long v, int m) {
  unsigned lo = (unsigned)v, hi = (unsigned)(v >> 32);
  lo = __shfl_xor(lo, m, 64);
  hi = __shfl_xor(hi, m, 64);
  return ((unsigned long long)hi << 32) | lo;
}

__device__ __forceinline__ ushort f2bf(float f) {  // RNE float->bf16
  unsigned u = __float_as_uint(f);
  u += 0x7FFFu + ((u >> 16) & 1u);
  return (ushort)(u >> 16);
}

__device__ __forceinline__ unsigned f2s(float f) {  // order-preserving float->u32
  unsigned b = __float_as_uint(f);
  return b ^ (unsigned)(((int)b >> 31) | 0x80000000);
}

// ---------------- init ----------------
__global__ void k_init(float* __restrict__ lacc) {
  if (threadIdx.x < 16) lacc[threadIdx.x] = 0.f;
}

// ---------------- weight-norm prep: w = v * (g / ||v||_row) ----------------
__global__ void k_prep_w(const float* __restrict__ V, const float* __restrict__ G,
                         float* __restrict__ W, int RL) {
  int o = blockIdx.x, tid = threadIdx.x;
  float s = 0.f;
  for (int i = tid; i < RL; i += 256) { float v = V[(size_t)o * RL + i]; s = fmaf(v, v, s); }
  __shared__ float scratch[4];
  s = block_reduce_sum(s, scratch);
  __shared__ float sc;
  if (tid == 0) sc = G[o] / sqrtf(s);
  __syncthreads();
  float scale = sc;
  for (int i = tid; i < RL; i += 256) W[(size_t)o * RL + i] = V[(size_t)o * RL + i] * scale;
}

// ---------------- normalized codebook + row sq-norms ----------------
__global__ void k_prep_cn(const float* __restrict__ CB, float* __restrict__ Cn,
                          float* __restrict__ C2) {
  int k = blockIdx.x, tid = threadIdx.x;  // 256 threads = 256 dims
  float v = CB[(size_t)k * 256 + tid];
  __shared__ float scratch[4];
  float s = block_reduce_sum(v * v, scratch);
  __shared__ float sm;
  if (tid == 0) sm = fmaxf(sqrtf(s), 1e-12f);
  __syncthreads();
  float cn = v / sm;
  Cn[(size_t)k * 256 + tid] = cn;
  float s2 = block_reduce_sum(cn * cn, scratch);
  if (tid == 0) C2[k] = s2;
}

// ---------------- bf16 mirror of normalized codebook ----------------
__global__ void k_cvt_cn(const float* __restrict__ Cn, ushort* __restrict__ CB16) {
  int i = blockIdx.x * 256 + threadIdx.x;  // 524288 float4s
  float4 v = ((const float4*)Cn)[i];
  ushort4 o;
  o.x = f2bf(v.x); o.y = f2bf(v.y); o.z = f2bf(v.z); o.w = f2bf(v.w);
  ((ushort4*)CB16)[i] = o;
}

// ---------------- bf16 mirror of w1 (RNE), into dead z_pooled tail ----------------
__global__ void k_cvt_w1b(const float* __restrict__ W1, ushort* __restrict__ W1B) {
  int i = blockIdx.x * 256 + threadIdx.x;  // 65536 float4s
  float4 v = ((const float4*)W1)[i];
  ushort4 o;
  o.x = f2bf(v.x); o.y = f2bf(v.y); o.z = f2bf(v.z); o.w = f2bf(v.w);
  ((ushort4*)W1B)[i] = o;
}

// ---------------- pool z by 4 along t (commutes with 1x1 conv) ----------------
__global__ void k_pool(const float* __restrict__ Z, float* __restrict__ ZP) {
  int i = blockIdx.x * 256 + threadIdx.x;  // 16,777,216
  float4 v = ((const float4*)Z)[i];
  ZP[i] = (v.x + v.y + v.z + v.w) * 0.25f;
}

// ---------------- inter GEMM (Kahan), TRANSPOSED out: ITT[n][d] ----------------
#define IBM 64
#define IBN 64
__global__ __launch_bounds__(256) void k_gemm_inter(
    const float* __restrict__ W1, const float* __restrict__ ZP,
    const float* __restrict__ B1, float* __restrict__ ITT) {
  int tid = threadIdx.x;
  int n0g = blockIdx.x * IBN;  // 0..16383
  int m0 = blockIdx.y * IBM;   // 0..255
  int b = n0g >> 10, s0 = n0g & 1023;
  const float* Zb = ZP + ((size_t)b << 20);
  __shared__ float As[BK][IBM + 4];
  __shared__ float Bs[BK][IBN + 4];
  float acc[4][4], comp[4][4];
#pragma unroll
  for (int i = 0; i < 4; i++)
#pragma unroll
    for (int j = 0; j < 4; j++) { acc[i][j] = 0.f; comp[i][j] = 0.f; }
  int tx = tid & 15, ty = tid >> 4;
  int am = tid >> 2, ac4 = tid & 3;
  int bk = tid >> 4, bf4 = tid & 15;
  for (int k0 = 0; k0 < 1024; k0 += BK) {
    float4 a = *(const float4*)&W1[(size_t)(m0 + am) * 1024 + k0 + ac4 * 4];
    As[ac4 * 4 + 0][am] = a.x; As[ac4 * 4 + 1][am] = a.y;
    As[ac4 * 4 + 2][am] = a.z; As[ac4 * 4 + 3][am] = a.w;
    float4 v = *(const float4*)&Zb[(size_t)(k0 + bk) * 1024 + s0 + bf4 * 4];
    *(float4*)&Bs[bk][bf4 * 4] = v;
    __syncthreads();
    float ch[4][4];
#pragma unroll
    for (int i = 0; i < 4; i++)
#pragma unroll
      for (int j = 0; j < 4; j++) ch[i][j] = 0.f;
#pragma unroll
    for (int k = 0; k < BK; k++) {
      float4 a4 = *(const float4*)&As[k][ty * 4];
      float4 b4 = *(const float4*)&Bs[k][tx * 4];
      float av[4] = {a4.x, a4.y, a4.z, a4.w};
      float bv[4] = {b4.x, b4.y, b4.z, b4.w};
#pragma unroll
      for (int i = 0; i < 4; i++)
#pragma unroll
        for (int j = 0; j < 4; j++) ch[i][j] = fmaf(av[i], bv[j], ch[i][j]);
    }
    // Kahan-compensated fold of this K-chunk
#pragma unroll
    for (int i = 0; i < 4; i++)
#pragma unroll
      for (int j = 0; j < 4; j++) {
        float y = ch[i][j] - comp[i][j];
        float t = acc[i][j] + y;
        comp[i][j] = (t - acc[i][j]) - y;
        acc[i][j] = t;
      }
    __syncthreads();
  }
  float b0 = B1[m0 + ty * 4 + 0];
  float b1v = B1[m0 + ty * 4 + 1];
  float b2v = B1[m0 + ty * 4 + 2];
  float b3v = B1[m0 + ty * 4 + 3];
#pragma unroll
  for (int j = 0; j < 4; j++) {
    int n = n0g + tx * 4 + j;
    *(float4*)&ITT[(size_t)n * 256 + m0 + ty * 4] =
        make_float4(acc[0][j] + b0, acc[1][j] + b1v, acc[2][j] + b2v, acc[3][j] + b3v);
  }
}

// ---------------- normalize rows of ITT (queries), emit bf16 + e2 ----------------
__global__ void k_norm(float* __restrict__ ITT, ushort* __restrict__ QB,
                       float* __restrict__ E2) {
  int w = threadIdx.x >> 6, l = threadIdx.x & 63;
  int n = blockIdx.x * 4 + w;  // 4096 blocks
  float4 v = *(const float4*)&ITT[(size_t)n * 256 + l * 4];
  float s = fmaf(v.x, v.x, fmaf(v.y, v.y, fmaf(v.z, v.z, v.w * v.w)));
#pragma unroll
  for (int sh = 1; sh < 64; sh <<= 1) s += __shfl_xor(s, sh, 64);
  float m = fmaxf(sqrtf(s), 1e-12f);
  float4 o;
  o.x = v.x / m; o.y = v.y / m; o.z = v.z / m; o.w = v.w / m;
  *(float4*)&ITT[(size_t)n * 256 + l * 4] = o;
  ushort4 q;
  q.x = f2bf(o.x); q.y = f2bf(o.y); q.z = f2bf(o.z); q.w = f2bf(o.w);
  *(ushort4*)&QB[(size_t)n * 256 + l * 4] = q;
  float s2 = fmaf(o.x, o.x, fmaf(o.y, o.y, fmaf(o.z, o.z, o.w * o.w)));
#pragma unroll
  for (int sh = 1; sh < 64; sh <<= 1) s2 += __shfl_xor(s2, sh, 64);
  if (l == 0) E2[n] = s2;
}

// ---------------- GEMM1 via MFMA: z_e = W1 @ z + b1 (bf16 inputs, f32 acc) ----------------
// Block: 256m x 64n, K=1024. 4 waves, each 64m x 64n (4x4 of 16x16x32 bf16).
// A (W1 bf16) direct global->reg (L2-resident). B (z f32 [k][t]) staged in LDS,
// fragments built by 2 scalar reads + truncate-pack. Epilogue: per-wave LDS transpose,
// FULLY UNROLLED so acc stays in AGPRs (runtime indexing demotes to scratch -> 2.5GB
// HBM write amplification, measured round 2).
__global__ __launch_bounds__(256) void k_gemm1m(
    const ushort* __restrict__ W1B, const float* __restrict__ Z,
    const float* __restrict__ B1, float* __restrict__ ZE) {
  int tid = threadIdx.x;
  int n0g = blockIdx.x * 64;  // global t across batches
  int b = n0g >> 12, t0 = n0g & 4095;
  const float* Zb = Z + ((size_t)b << 22);  // b*1024*4096
  __shared__ float Bs[32][65];
  __shared__ float LT[4][16][66];
  int lane = tid & 63, wid = tid >> 6;
  int lc = lane & 15, lh = lane >> 4;
  f32x4 acc[4][4];
#pragma unroll
  for (int i = 0; i < 4; i++)
#pragma unroll
    for (int j = 0; j < 4; j++) acc[i][j] = (f32x4){0.f, 0.f, 0.f, 0.f};
  // A fragment base: row m = wid*64 + i*16 + lc, k-offset lh*8
  const ushort* Abase = W1B + (size_t)(wid * 64 + lc) * 1024 + lh * 8;
  for (int k0 = 0; k0 < 1024; k0 += 32) {
    // B staging: 32k x 64t floats = 512 float4s; thread handles float4 ids tid*2+{0,1}
    float4 zv[2];
#pragma unroll
    for (int it = 0; it < 2; it++) {
      int idx = tid * 2 + it;
      int k = idx >> 4, c4 = idx & 15;
      zv[it] = *(const float4*)&Zb[(size_t)(k0 + k) * 4096 + t0 + c4 * 4];
    }
    bf16x8 af[4];
#pragma unroll
    for (int i = 0; i < 4; i++)
      af[i] = *(const bf16x8*)(Abase + (size_t)i * 16384 + k0);
    __syncthreads();  // prior iteration's Bs reads done
#pragma unroll
    for (int it = 0; it < 2; it++) {
      int idx = tid * 2 + it;
      int k = idx >> 4, c4 = idx & 15;
      *(float4*)&Bs[k][c4 * 4] = zv[it];
    }
    __syncthreads();
    // build B fragments: lane lc -> col, lh -> k-octet; truncate f32->bf16
    bf16x8 bq[4];
#pragma unroll
    for (int j = 0; j < 4; j++) {
      int col = j * 16 + lc;
      unsigned bw[4];
#pragma unroll
      for (int p = 0; p < 4; p++) {
        unsigned u0 = __float_as_uint(Bs[lh * 8 + 2 * p + 0][col]);
        unsigned u1 = __float_as_uint(Bs[lh * 8 + 2 * p + 1][col]);
        bw[p] = (u1 & 0xFFFF0000u) | (u0 >> 16);
      }
      bq[j] = *reinterpret_cast<bf16x8*>(bw);
    }
#pragma unroll
    for (int i = 0; i < 4; i++)
#pragma unroll
      for (int j = 0; j < 4; j++)
        acc[i][j] = __builtin_amdgcn_mfma_f32_16x16x32_bf16(af[i], bq[j], acc[i][j], 0, 0, 0);
  }
  // epilogue: per-wave LDS transpose (wave-private tile; no barriers needed),
  // fully unrolled -> acc never runtime-indexed.
  float* C = ZE + (size_t)b * 256 * 4096;
#pragma unroll
  for (int i = 0; i < 4; i++) {
#pragma unroll
    for (int j = 0; j < 4; j++)
#pragma unroll
      for (int r = 0; r < 4; r++)
        LT[wid][lh * 4 + r][j * 16 + lc] = acc[i][j][r];
#pragma unroll
    for (int mr = 0; mr < 16; mr++) {
      int m = wid * 64 + i * 16 + mr;
      C[(size_t)m * 4096 + t0 + lane] = LT[wid][mr][lane] + B1[m];
    }
  }
}

// ---------------- dist approx: bf16 MFMA, per-32-candidate-subtile minima ----------------
// A = CnBf [8192][256] (M=candidates), B = QBf [16384][256] (N=queries)
// score = c2[m] - 2*dot_bf16;  TMIN[sub 256][n 16384] = min over subtile
#define DBKP 72  // 64 + 8 bf16 pad (16B) -> row stride 144B
__global__ __launch_bounds__(256) void k_dist_approx(
    const ushort* __restrict__ CnB, const ushort* __restrict__ QB,
    const float* __restrict__ C2, float* __restrict__ TMIN) {
  int tid = threadIdx.x;
  int n0 = blockIdx.x * 128;  // queries
  int m0 = blockIdx.y * 128;  // candidates
  __shared__ __align__(16) ushort As[128][DBKP];  // candidates
  __shared__ __align__(16) ushort Bs[128][DBKP];  // queries
  __shared__ float c2s[128];
  __shared__ float smin[4][128];
  int lane = tid & 63, wid = tid >> 6;
  int wm = wid >> 1, wn = wid & 1;
  int lc = lane & 15, lh = lane >> 4;
  f32x4 acc[4][4];
#pragma unroll
  for (int i = 0; i < 4; i++)
#pragma unroll
    for (int j = 0; j < 4; j++) acc[i][j] = (f32x4){0.f, 0.f, 0.f, 0.f};
  if (tid < 128) c2s[tid] = C2[m0 + tid];
  int row = tid >> 1, chunk = tid & 1;
  const ushort* gA = CnB + (size_t)(m0 + row) * 256 + chunk * 32;
  const ushort* gB = QB + (size_t)(n0 + row) * 256 + chunk * 32;
  for (int k0 = 0; k0 < 256; k0 += 64) {
    float4 a0 = *(const float4*)(gA + k0);
    float4 a1 = *(const float4*)(gA + k0 + 8);
    float4 a2 = *(const float4*)(gA + k0 + 16);
    float4 a3 = *(const float4*)(gA + k0 + 24);
    float4 b0 = *(const float4*)(gB + k0);
    float4 b1 = *(const float4*)(gB + k0 + 8);
    float4 b2 = *(const float4*)(gB + k0 + 16);
    float4 b3 = *(const float4*)(gB + k0 + 24);
    __syncthreads();  // prior iteration's frag reads done
    *(float4*)&As[row][chunk * 32 + 0] = a0;
    *(float4*)&As[row][chunk * 32 + 8] = a1;
    *(float4*)&As[row][chunk * 32 + 16] = a2;
    *(float4*)&As[row][chunk * 32 + 24] = a3;
    *(float4*)&Bs[row][chunk * 32 + 0] = b0;
    *(float4*)&Bs[row][chunk * 32 + 8] = b1;
    *(float4*)&Bs[row][chunk * 32 + 16] = b2;
    *(float4*)&Bs[row][chunk * 32 + 24] = b3;
    __syncthreads();
#pragma unroll
    for (int kk = 0; kk < 64; kk += 32) {
      bf16x8 af[4], bfr[4];
#pragma unroll
      for (int i = 0; i < 4; i++) {
        af[i] = *(const bf16x8*)&As[wm * 64 + i * 16 + lc][kk + lh * 8];
        bfr[i] = *(const bf16x8*)&Bs[wn * 64 + i * 16 + lc][kk + lh * 8];
      }
#pragma unroll
      for (int i = 0; i < 4; i++)
#pragma unroll
        for (int j = 0; j < 4; j++)
          acc[i][j] = __builtin_amdgcn_mfma_f32_16x16x32_bf16(af[i], bfr[j], acc[i][j], 0, 0, 0);
    }
  }
  // per-lane min over (i, r) split into 32-row halves; D: row=(lh*4+r), col=lc
  float vmin0[4], vmin1[4];
#pragma unroll
  for (int j = 0; j < 4; j++) {
    float mA = 3.4e38f, mB = 3.4e38f;
#pragma unroll
    for (int i = 0; i < 4; i++) {
#pragma unroll
      for (int r = 0; r < 4; r++) {
        float s = c2s[wm * 64 + i * 16 + lh * 4 + r] - 2.f * acc[i][j][r];
        if (i < 2) mA = fminf(mA, s); else mB = fminf(mB, s);
      }
    }
    vmin0[j] = mA; vmin1[j] = mB;
  }
#pragma unroll
  for (int j = 0; j < 4; j++) {
    vmin0[j] = fminf(vmin0[j], __shfl_xor(vmin0[j], 16, 64));
    vmin0[j] = fminf(vmin0[j], __shfl_xor(vmin0[j], 32, 64));
    vmin1[j] = fminf(vmin1[j], __shfl_xor(vmin1[j], 16, 64));
    vmin1[j] = fminf(vmin1[j], __shfl_xor(vmin1[j], 32, 64));
  }
  // writer: lane handles j == lh for its column lc
  float w0 = (lh == 0) ? vmin0[0] : (lh == 1) ? vmin0[1] : (lh == 2) ? vmin0[2] : vmin0[3];
  float w1 = (lh == 0) ? vmin1[0] : (lh == 1) ? vmin1[1] : (lh == 2) ? vmin1[2] : vmin1[3];
  smin[wm * 2 + 0][wn * 64 + lh * 16 + lc] = w0;
  smin[wm * 2 + 1][wn * 64 + lh * 16 + lc] = w1;
  __syncthreads();
  if (tid < 128) {
#pragma unroll
    for (int sub = 0; sub < 4; sub++)
      TMIN[(size_t)(blockIdx.y * 4 + sub) * 16384 + n0 + tid] = smin[sub][tid];
  }
}

// ---------------- exact refine: fp64 dots on qualifying subtiles ----------------
#define RMARGIN 0.035f  // > 2*eps, eps <= 2^-6 (worst-case bf16 rounding, |q|=|c|=1)
__global__ __launch_bounds__(128) void k_refine(
    const float* __restrict__ TMIN, const float* __restrict__ ITT,
    const float* __restrict__ Cn, const float* __restrict__ C2,
    const float* __restrict__ E2, int* __restrict__ IDX, float* __restrict__ OUTI) {
  int n = blockIdx.x, t = threadIdx.x;
  __shared__ __align__(16) float qs[256];
  __shared__ float tm[256];
  __shared__ int qlist[256];
  __shared__ int qcount;
  __shared__ float mus[2];
  __shared__ double parts[4][32];
  qs[t] = ITT[(size_t)n * 256 + t];
  qs[t + 128] = ITT[(size_t)n * 256 + 128 + t];
  tm[t] = TMIN[(size_t)t * 16384 + n];
  tm[t + 128] = TMIN[(size_t)(t + 128) * 16384 + n];
  if (t == 0) qcount = 0;
  __syncthreads();
  float mu = fminf(tm[t], tm[t + 128]);
#pragma unroll
  for (int s = 1; s < 64; s <<= 1) mu = fminf(mu, __shfl_xor(mu, s, 64));
  if ((t & 63) == 0) mus[t >> 6] = mu;
  __syncthreads();
  float thr = fminf(mus[0], mus[1]) + RMARGIN;
  for (int s = t; s < 256; s += 128)
    if (tm[s] <= thr) { int p = atomicAdd(&qcount, 1); qlist[p] = s; }
  __syncthreads();
  int Q = qcount;
  unsigned long long best = ~0ull;
  float e2n = E2[n];
  int c = t & 31, kc = t >> 5;
  for (int qi = 0; qi < Q; qi++) {
    int sub = qlist[qi];
    int m = sub * 32 + c;
    const float* cr = Cn + (size_t)m * 256 + kc * 64;
    const float* qq = qs + kc * 64;
    double p = 0.0;
#pragma unroll 4
    for (int k = 0; k < 64; k += 4) {
      float4 c4 = *(const float4*)&cr[k];
      float4 q4 = *(const float4*)&qq[k];
      p += (double)c4.x * (double)q4.x + (double)c4.y * (double)q4.y +
           (double)c4.z * (double)q4.z + (double)c4.w * (double)q4.w;
    }
    parts[kc][c] = p;
    __syncthreads();
    if (t < 32) {
      double dot = (parts[0][t] + parts[1][t]) + (parts[2][t] + parts[3][t]);
      float dist = (float)((double)e2n - 2.0 * dot + (double)C2[sub * 32 + t]);
      unsigned long long pk =
          ((unsigned long long)f2s(dist) << 32) | (unsigned)(sub * 32 + t);
      best = (pk < best) ? pk : best;
    }
    __syncthreads();
  }
  if (t < 32) {
#pragma unroll
    for (int s = 1; s <= 16; s <<= 1) {
      unsigned long long o = shfl_xor_u64(best, s);
      best = (o < best) ? o : best;
    }
    if (t == 0) {
      int idx = (int)(best & 0xFFFFFFFFull);
      IDX[n] = idx;
      OUTI[n] = (float)idx;
    }
  }
}

// ---------------- table GEMM: TT[k][o] = sum_d CB[k][d] * W2[o][d] ----------------
__global__ __launch_bounds__(256) void k_table(
    const float* __restrict__ CB, const float* __restrict__ W2,
    float* __restrict__ TT) {
  int tid = threadIdx.x;
  int n0 = blockIdx.x * BN;  // o tile (1024 -> 8)
  int m0 = blockIdx.y * BM;  // codebook tile (8192 -> 64)
  __shared__ float As[BK][LDSP];
  __shared__ float Bs[BK][LDSP];
  float acc[8][8];
#pragma unroll
  for (int i = 0; i < 8; i++)
#pragma unroll
    for (int j = 0; j < 8; j++) acc[i][j] = 0.f;
  int tx = tid & 15, ty = tid >> 4;
  int am = tid >> 1, ac4 = tid & 1;
  for (int k0 = 0; k0 < 256; k0 += BK) {
#pragma unroll
    for (int h = 0; h < 2; h++) {
      int c4 = ac4 + h * 2;
      float4 a = *(const float4*)&CB[(size_t)(m0 + am) * 256 + k0 + c4 * 4];
      As[c4 * 4 + 0][am] = a.x; As[c4 * 4 + 1][am] = a.y;
      As[c4 * 4 + 2][am] = a.z; As[c4 * 4 + 3][am] = a.w;
      float4 b = *(const float4*)&W2[(size_t)(n0 + am) * 256 + k0 + c4 * 4];
      Bs[c4 * 4 + 0][am] = b.x; Bs[c4 * 4 + 1][am] = b.y;
      Bs[c4 * 4 + 2][am] = b.z; Bs[c4 * 4 + 3][am] = b.w;
    }
    __syncthreads();
#pragma unroll
    for (int k = 0; k < BK; k++) {
      float4 a0 = *(const float4*)&As[k][ty * 4];
      float4 a1 = *(const float4*)&As[k][ty * 4 + 64];
      float4 b0 = *(const float4*)&Bs[k][tx * 4];
      float4 b1 = *(const float4*)&Bs[k][tx * 4 + 64];
      float av[8] = {a0.x, a0.y, a0.z, a0.w, a1.x, a1.y, a1.z, a1.w};
      float bv[8] = {b0.x, b0.y, b0.z, b0.w, b1.x, b1.y, b1.z, b1.w};
#pragma unroll
      for (int i = 0; i < 8; i++)
#pragma unroll
        for (int j = 0; j < 8; j++) acc[i][j] = fmaf(av[i], bv[j], acc[i][j]);
    }
    __syncthreads();
  }
#pragma unroll
  for (int i = 0; i < 8; i++) {
    int m = m0 + ((i < 4) ? (ty * 4 + i) : (64 + ty * 4 + (i - 4)));
    *(float4*)&TT[(size_t)m * 1024 + n0 + tx * 4] =
        make_float4(acc[i][0], acc[i][1], acc[i][2], acc[i][3]);
    *(float4*)&TT[(size_t)m * 1024 + n0 + 64 + tx * 4] =
        make_float4(acc[i][4], acc[i][5], acc[i][6], acc[i][7]);
  }
}

// ---------------- gather table rows + linear upsample + bias ----------------
__global__ __launch_bounds__(256) void k_upsample(
    const float* __restrict__ TT, const int* __restrict__ IDX,
    const float* __restrict__ B2, float* __restrict__ OUT) {
  int tid = threadIdx.x;
  int t0 = blockIdx.x * 64;
  int o0 = blockIdx.y * 64;
  int b = blockIdx.z;
  int s_lo = (t0 == 0) ? 0 : (t0 / 4 - 1);
  int s_hi = min(t0 / 4 + 16, 1023);
  int cnt = s_hi - s_lo + 1;  // <= 18
  __shared__ float rows[18 * 65];
  for (int q = tid; q < cnt * 64; q += 256) {
    int r = q >> 6, oc = q & 63;
    int ti = IDX[b * 1024 + s_lo + r];
    rows[r * 65 + oc] = TT[(size_t)ti * 1024 + o0 + oc];
  }
  __syncthreads();
  int tl = tid & 63, og = tid >> 6;
  int t = t0 + tl;
  float src = fmaxf((t + 0.5f) * 0.25f - 0.5f, 0.f);
  int i0 = (int)src;
  float fr = src - (float)i0;
  int i1 = min(i0 + 1, 1023);
  int r0 = i0 - s_lo, r1 = i1 - s_lo;
  float* outb = OUT + (size_t)b * 1024 * 4096;
#pragma unroll
  for (int j = 0; j < 16; j++) {
    int o = o0 + og * 16 + j;
    float v = rows[r0 * 65 + og * 16 + j] * (1.f - fr) +
              rows[r1 * 65 + og * 16 + j] * fr + B2[o];
    outb[(size_t)o * 4096 + t] = v;
  }
}

// ---------------- loss: mean((z_e - upsample(cb[idx]))^2) per batch ----------------
__global__ __launch_bounds__(256) void k_loss(
    const float* __restrict__ ZE, const float* __restrict__ CB,
    const int* __restrict__ IDX, float* __restrict__ LACC) {
  int tid = threadIdx.x;
  int t0 = blockIdx.x * 64;
  int b = blockIdx.y;
  int s_lo = (t0 == 0) ? 0 : (t0 / 4 - 1);
  int s_hi = min(t0 / 4 + 16, 1023);
  int cnt = s_hi - s_lo + 1;
  __shared__ float crow[18 * 257];
  for (int q = tid; q < cnt * 256; q += 256) {
    int r = q >> 8, d = q & 255;
    int ti = IDX[b * 1024 + s_lo + r];
    crow[r * 257 + d] = CB[(size_t)ti * 256 + d];
  }
  __syncthreads();
  int tl = tid & 63, dg = tid >> 6;
  int t = t0 + tl;
  float src = fmaxf((t + 0.5f) * 0.25f - 0.5f, 0.f);
  int i0 = (int)src;
  float fr = src - (float)i0;
  int i1 = min(i0 + 1, 1023);
  int r0 = i0 - s_lo, r1 = i1 - s_lo;
  const float* zeb = ZE + (size_t)b * 256 * 4096;
  float acc = 0.f;
  for (int j = 0; j < 64; j++) {
    int d = dg * 64 + j;
    float zq = crow[r0 * 257 + d] * (1.f - fr) + crow[r1 * 257 + d] * fr;
    float diff = zeb[(size_t)d * 4096 + t] - zq;
    acc = fmaf(diff, diff, acc);
  }
  __shared__ float scratch[4];
  acc = block_reduce_sum(acc, scratch);
  if (tid == 0) atomicAdd(&LACC[b], acc);
}

__global__ void k_loss_final(const float* __restrict__ LACC, float* __restrict__ OUTL) {
  int t = threadIdx.x;  // 32
  OUTL[t] = LACC[t & 15] * (1.f / 1048576.f);
}

// ---------------- launch ----------------
extern "C" void kernel_launch(void* const* d_in, const int* in_sizes, int n_in,
                              void* d_out, int out_size, void* d_ws, size_t ws_size,
                              hipStream_t stream) {
  (void)in_sizes; (void)n_in; (void)out_size; (void)ws_size;
  const float* z   = (const float*)d_in[0];
  const float* ipv = (const float*)d_in[1];
  const float* ipg = (const float*)d_in[2];
  const float* ipb = (const float*)d_in[3];
  const float* opv = (const float*)d_in[4];
  const float* opg = (const float*)d_in[5];
  const float* opb = (const float*)d_in[6];
  const float* cb  = (const float*)d_in[7];

  float* out = (float*)d_out;
  float* ws  = (float*)d_ws;

  float* w1 = ws + W1_OFF;
  float* w2 = ws + W2_OFF;
  float* cn = ws + CN_OFF;
  float* c2 = ws + C2_OFF;
  float* e2 = ws + E2_OFF;
  float* lacc = ws + LACC_OFF;
  int*   idx = (int*)(ws + IDX_OFF);
  float* itt = ws + IT_OFF;
  float* big = ws + BIG_OFF;  // z_pooled, then table
  ushort* qbf  = (ushort*)(ws + BIG_OFF + 8388608LL);
  ushort* cbf  = (ushort*)(ws + BIG_OFF + 10485760LL);
  float*  tmin = ws + BIG_OFF + 11534336LL;
  ushort* w1b  = (ushort*)(ws + BIG_OFF + 15728640LL);

  float* out_zq = out + OUT_ZQ;
  float* out_loss = out + OUT_LOSS;
  float* out_idx = out + OUT_IDX;
  float* out_ze = out + OUT_ZE;

  hipLaunchKernelGGL(k_init, dim3(1), dim3(64), 0, stream, lacc);
  hipLaunchKernelGGL(k_prep_w, dim3(256), dim3(256), 0, stream, ipv, ipg, w1, 1024);
  hipLaunchKernelGGL(k_prep_w, dim3(1024), dim3(256), 0, stream, opv, opg, w2, 256);
  hipLaunchKernelGGL(k_prep_cn, dim3(8192), dim3(256), 0, stream, cb, cn, c2);
  hipLaunchKernelGGL(k_pool, dim3(65536), dim3(256), 0, stream, z, big);
  hipLaunchKernelGGL(k_gemm_inter, dim3(256, 4), dim3(256), 0, stream, w1, big, ipb, itt);
  hipLaunchKernelGGL(k_norm, dim3(4096), dim3(256), 0, stream, itt, qbf, e2);
  hipLaunchKernelGGL(k_cvt_cn, dim3(2048), dim3(256), 0, stream, cn, cbf);
  hipLaunchKernelGGL(k_cvt_w1b, dim3(256), dim3(256), 0, stream, w1, w1b);
  hipLaunchKernelGGL(k_gemm1m, dim3(1024), dim3(256), 0, stream, w1b, z, ipb, out_ze);
  hipLaunchKernelGGL(k_dist_approx, dim3(128, 64), dim3(256), 0, stream, cbf, qbf, c2, tmin);
  hipLaunchKernelGGL(k_refine, dim3(16384), dim3(128), 0, stream, tmin, itt, cn, c2, e2,
                     idx, out_idx);
  hipLaunchKernelGGL(k_table, dim3(8, 64), dim3(256), 0, stream, cb, w2, big);
  hipLaunchKernelGGL(k_upsample, dim3(64, 16, 16), dim3(256), 0, stream, big, idx, opb, out_zq);
  hipLaunchKernelGGL(k_loss, dim3(64, 16), dim3(256), 0, stream, out_ze, cb, idx, lacc);
  hipLaunchKernelGGL(k_loss_final, dim3(1), dim3(32), 0, stream, lacc, out_loss);
}